// Round 1
// baseline (520.482 us; speedup 1.0000x reference)
//
#include <hip/hip_runtime.h>

// Problem constants (match reference)
#define B_SZ   8
#define NUMR   128            // num
#define L_SZ   (NUMR * NUMR)  // 16384
#define HH     8              // heads
#define DK     64
#define CC     512            // H*DK
#define EPSV   1e-8f

#define ROWS_PER_WAVE 8       // 8 rows x 8 heads = 64 results = 1 store/lane

// ---------------------------------------------------------------------------
// Kernel 1: cosine similarity + ReLU, restructured for streaming BW.
//  - one wave owns 8 consecutive (b,l) rows (16 KiB of q + 16 KiB of k)
//  - DENSE loads: lane i loads float4 #i of the row -> each instruction
//    covers one contiguous 1 KiB span (no 32B-stride half-used lines)
//  - head mapping: load0 lanes [16g,16g+16) hold floats [64g,64g+64) = head g;
//    load1 same lanes = head 4+g. 16-lane reduce with DPP-friendly offsets.
//  - normalize via rsqrt:  dot / max(|q||k|,eps) == dot * rsqrt(max(qq*kk,eps^2))
//  - results for 8 rows x 8 heads accumulate into one register; single
//    coalesced 256 B store per wave at the end.
// Block 0 additionally zeroes the 128-entry column mask in workspace.
// ---------------------------------------------------------------------------
__global__ __launch_bounds__(256) void cos_attn_kernel(
    const float4* __restrict__ q4, const float4* __restrict__ k4,
    float* __restrict__ attn, unsigned int* __restrict__ colmask) {
  if (blockIdx.x == 0 && threadIdx.x < NUMR) colmask[threadIdx.x] = 0u;

  const int wave = (blockIdx.x * blockDim.x + threadIdx.x) >> 6;
  const int lane = threadIdx.x & 63;
  const int row0 = wave * ROWS_PER_WAVE;   // first of 8 consecutive rows

  float outv = 0.0f;  // this lane's final value: row (lane>>3), head (lane&7)

#pragma unroll 2
  for (int r = 0; r < ROWS_PER_WAVE; ++r) {
    const size_t base = (size_t)(row0 + r) * (CC / 4);
    const float4 a0 = q4[base + lane];        // dense 1 KiB per instruction
    const float4 a1 = q4[base + 64 + lane];
    const float4 b0 = k4[base + lane];
    const float4 b1 = k4[base + 64 + lane];

    float dot0 = a0.x * b0.x + a0.y * b0.y + a0.z * b0.z + a0.w * b0.w;
    float qq0  = a0.x * a0.x + a0.y * a0.y + a0.z * a0.z + a0.w * a0.w;
    float kk0  = b0.x * b0.x + b0.y * b0.y + b0.z * b0.z + b0.w * b0.w;
    float dot1 = a1.x * b1.x + a1.y * b1.y + a1.z * b1.z + a1.w * b1.w;
    float qq1  = a1.x * a1.x + a1.y * a1.y + a1.z * a1.z + a1.w * a1.w;
    float kk1  = b1.x * b1.x + b1.y * b1.y + b1.z * b1.z + b1.w * b1.w;

    // 16-lane group reduction (offsets < 16 -> DPP row ops)
#pragma unroll
    for (int off = 1; off < 16; off <<= 1) {
      dot0 += __shfl_xor(dot0, off, 64);
      qq0  += __shfl_xor(qq0,  off, 64);
      kk0  += __shfl_xor(kk0,  off, 64);
      dot1 += __shfl_xor(dot1, off, 64);
      qq1  += __shfl_xor(qq1,  off, 64);
      kk1  += __shfl_xor(kk1,  off, 64);
    }

    // heads 0..3 on groups 0..3 (part0), heads 4..7 on groups 0..3 (part1)
    const float v0 = fmaxf(dot0 * rsqrtf(fmaxf(qq0 * kk0, EPSV * EPSV)), 0.0f);
    const float v1 = fmaxf(dot1 * rsqrtf(fmaxf(qq1 * kk1, EPSV * EPSV)), 0.0f);

    // res = head (lane&7)'s value for this row, valid on every lane
    const int src = (lane & 3) << 4;
    const float g0 = __shfl(v0, src, 64);
    const float g1 = __shfl(v1, src, 64);
    const float res = ((lane & 7) < 4) ? g0 : g1;
    if ((lane >> 3) == r) outv = res;
  }

  // one coalesced 256 B store per wave: attn[(row0 + lane>>3)*8 + (lane&7)]
  attn[(size_t)row0 * HH + lane] = outv;
}

// ---------------------------------------------------------------------------
// Kernel 2: per-(b, i, h) top-4 over j in [0,128), union into colmask.
// One wave per group; lane holds j=lane and j=lane+64. 4 rounds of
// argmax-with-tiebreak (higher value wins; equal value -> lower index wins,
// matching jax.lax.top_k stable descending semantics).
// ---------------------------------------------------------------------------
__global__ __launch_bounds__(256) void topk_kernel(
    const float* __restrict__ attn, unsigned int* __restrict__ colmask) {
  const int wave = (blockIdx.x * blockDim.x + threadIdx.x) >> 6;  // (b*num+i)*8+h
  const int lane = threadIdx.x & 63;

  const size_t base = (size_t)(wave >> 3) * (NUMR * HH) + (size_t)(wave & 7);
  float v0 = attn[base + (size_t)lane * HH];
  float v1 = attn[base + (size_t)(lane + 64) * HH];

#pragma unroll
  for (int rnd = 0; rnd < 4; ++rnd) {
    float bv;
    int bi;
    if (v1 > v0) { bv = v1; bi = lane + 64; } else { bv = v0; bi = lane; }
#pragma unroll
    for (int off = 1; off < 64; off <<= 1) {
      const float ov = __shfl_xor(bv, off, 64);
      const int   oi = __shfl_xor(bi, off, 64);
      if (ov > bv || (ov == bv && oi < bi)) { bv = ov; bi = oi; }
    }
    // bi now identical on all lanes: the round's winner
    if (bi == lane)            v0 = -1.0f;
    else if (bi == lane + 64)  v1 = -1.0f;
    if (lane == 0) colmask[bi] = 1u;  // racing identical writes: benign
  }
}

// ---------------------------------------------------------------------------
// Kernel 3: out[b,i,j,h] *= roi[b,i,j] * colmask[j]  (in place on d_out)
// One thread per (b,i,j): 8 head values as 2 x float4.
// ---------------------------------------------------------------------------
__global__ __launch_bounds__(256) void apply_kernel(
    float* __restrict__ out, const float* __restrict__ roi,
    const unsigned int* __restrict__ colmask) {
  const int t = blockIdx.x * blockDim.x + threadIdx.x;  // (b*num+i)*num+j
  const float s = roi[t] * (colmask[t & (NUMR - 1)] ? 1.0f : 0.0f);
  float4* p = (float4*)(out + (size_t)t * 8);
  float4 x0 = p[0], x1 = p[1];
  x0.x *= s; x0.y *= s; x0.z *= s; x0.w *= s;
  x1.x *= s; x1.y *= s; x1.z *= s; x1.w *= s;
  p[0] = x0;
  p[1] = x1;
}

extern "C" void kernel_launch(void* const* d_in, const int* in_sizes, int n_in,
                              void* d_out, int out_size, void* d_ws, size_t ws_size,
                              hipStream_t stream) {
  const float4* q   = (const float4*)d_in[0];  // (B, num, num, C) fp32
  const float4* k   = (const float4*)d_in[1];  // (B, num, num, C) fp32
  const float* roi  = (const float*)d_in[2];   // (B, num, num)    fp32
  float* out = (float*)d_out;                  // (B, num, num, H) fp32 == attn scratch
  unsigned int* colmask = (unsigned int*)d_ws; // 128 entries

  // Kernel 1: B*L/8 = 16384 waves, 4 waves/block -> 4096 blocks
  cos_attn_kernel<<<(B_SZ * L_SZ) / (ROWS_PER_WAVE * 4), 256, 0, stream>>>(
      q, k, out, colmask);

  // Kernel 2: B*num*H = 8192 waves -> 2048 blocks
  topk_kernel<<<(B_SZ * NUMR * HH) / 4, 256, 0, stream>>>(out, colmask);

  // Kernel 3: B*num*num = 131072 threads -> 512 blocks
  apply_kernel<<<(B_SZ * L_SZ) / 256, 256, 0, stream>>>(out, roi, colmask);
}